// Round 1
// baseline (363.247 us; speedup 1.0000x reference)
//
#include <hip/hip_runtime.h>

#define NBINS 256
#define NWAVES 16            /* 1024 threads / wave64 -> one private copy per wave */
#define STRENGTH 0.01f

// Kernel 1: grid-stride vectorized segment histogram.
// Per-WAVE private LDS histograms (no cross-wave same-address RMW hazards),
// 32-bit native LDS atomics (ds_add_f32 / ds_add_u32) instead of the slow
// 2-bank ds_add_u64 path. 2x unrolled loads for MLP.
__global__ __launch_bounds__(1024) void seg_hist_kernel(
    const float4* __restrict__ x4,
    const int4* __restrict__ idx4,
    float* __restrict__ gsum,
    unsigned int* __restrict__ gcnt,
    int nvec)
{
    __shared__ float        hsum[NWAVES][NBINS];   // 16 KiB
    __shared__ unsigned int hcnt[NWAVES][NBINS];   // 16 KiB

    for (int i = threadIdx.x; i < NWAVES * NBINS; i += blockDim.x) {
        ((float*)hsum)[i] = 0.0f;
        ((unsigned int*)hcnt)[i] = 0u;
    }
    __syncthreads();

    const int w = (threadIdx.x >> 6) & (NWAVES - 1);
    float*        hs = hsum[w];
    unsigned int* hc = hcnt[w];

    const int stride  = gridDim.x * blockDim.x;
    const int stride2 = stride << 1;

    for (int i = blockIdx.x * blockDim.x + threadIdx.x; i < nvec; i += stride2) {
        const float4 xa = x4[i];
        const int4   ia = idx4[i];
        const int j = i + stride;
        if (j < nvec) {
            const float4 xb = x4[j];       // second load pair in flight
            const int4   ib = idx4[j];
            atomicAdd(&hs[ia.x], xa.x);
            atomicAdd(&hs[ia.y], xa.y);
            atomicAdd(&hs[ia.z], xa.z);
            atomicAdd(&hs[ia.w], xa.w);
            atomicAdd(&hs[ib.x], xb.x);
            atomicAdd(&hs[ib.y], xb.y);
            atomicAdd(&hs[ib.z], xb.z);
            atomicAdd(&hs[ib.w], xb.w);
            atomicAdd(&hc[ia.x], 1u);
            atomicAdd(&hc[ia.y], 1u);
            atomicAdd(&hc[ia.z], 1u);
            atomicAdd(&hc[ia.w], 1u);
            atomicAdd(&hc[ib.x], 1u);
            atomicAdd(&hc[ib.y], 1u);
            atomicAdd(&hc[ib.z], 1u);
            atomicAdd(&hc[ib.w], 1u);
        } else {
            atomicAdd(&hs[ia.x], xa.x);
            atomicAdd(&hs[ia.y], xa.y);
            atomicAdd(&hs[ia.z], xa.z);
            atomicAdd(&hs[ia.w], xa.w);
            atomicAdd(&hc[ia.x], 1u);
            atomicAdd(&hc[ia.y], 1u);
            atomicAdd(&hc[ia.z], 1u);
            atomicAdd(&hc[ia.w], 1u);
        }
    }
    __syncthreads();

    // merge the 16 wave-private copies, flush one global atomic per bin per block
    for (int b = threadIdx.x; b < NBINS; b += blockDim.x) {
        float        s = 0.0f;
        unsigned int c = 0u;
        #pragma unroll
        for (int w2 = 0; w2 < NWAVES; ++w2) {
            s += hsum[w2][b];
            c += hcnt[w2][b];
        }
        atomicAdd(&gsum[b], s);
        atomicAdd(&gcnt[b], c);
    }
}

// Kernel 2: one block of 256 threads. Thread b owns bin b.
__global__ __launch_bounds__(NBINS) void finalize_kernel(
    const float* __restrict__ gsum,
    const unsigned int* __restrict__ gcnt,
    const float* __restrict__ target,
    float* __restrict__ out)
{
    const int t = threadIdx.x;
    const float s = gsum[t];
    const float c = (float)gcnt[t];
    const float mean = s / fmaxf(c, 1.0f);
    const float dev = mean - target[t];
    float v = dev * dev;

    #pragma unroll
    for (int off = 32; off > 0; off >>= 1) {
        v += __shfl_down(v, off, 64);
    }
    __shared__ float red[4];
    if ((t & 63) == 0) red[t >> 6] = v;
    __syncthreads();
    if (t == 0) {
        const float tot = red[0] + red[1] + red[2] + red[3];
        out[0] = tot * (STRENGTH / (float)NBINS);
    }
}

extern "C" void kernel_launch(void* const* d_in, const int* in_sizes, int n_in,
                              void* d_out, int out_size, void* d_ws, size_t ws_size,
                              hipStream_t stream)
{
    const float* x      = (const float*)d_in[0];
    const int*   idx    = (const int*)d_in[1];
    const float* target = (const float*)d_in[2];
    float*       out    = (float*)d_out;

    const int E    = in_sizes[0];
    const int nvec = E / 4;

    // workspace layout: [256 f32 sums][256 u32 counts]
    float*        gsum = (float*)d_ws;
    unsigned int* gcnt = (unsigned int*)(gsum + NBINS);

    hipMemsetAsync(d_ws, 0, NBINS * (sizeof(float) + sizeof(unsigned int)), stream);

    const int block = 1024;
    const int grid  = 512;  // 2 blocks/CU -> 32 waves/CU
    seg_hist_kernel<<<grid, block, 0, stream>>>(
        (const float4*)x, (const int4*)idx, gsum, gcnt, nvec);

    finalize_kernel<<<1, NBINS, 0, stream>>>(gsum, gcnt, target, out);
}